// Round 12
// baseline (6238.394 us; speedup 1.0000x reference)
//
#include <hip/hip_runtime.h>
#include <hip/hip_bf16.h>

#define SEQ    256
#define BATCH  64
#define EMB    256
#define HID    1024
#define GATES  3072   // 3*HID
#define NCLS   128
#define TCH    16                 // time chunk
#define ROWS   (TCH * BATCH)      // 1024 rows per chunk
#define NCH    (SEQ / TCH)        // 16 chunks
#define MX     (ROWS / 64)        // 16 m-tiles per GEMM

typedef __attribute__((ext_vector_type(8))) short bf16x8;
typedef __attribute__((ext_vector_type(4))) float f32x4;
typedef __attribute__((ext_vector_type(4))) unsigned int u32x4;
typedef __attribute__((ext_vector_type(2))) unsigned int u32x2;

__device__ inline unsigned short f2bf(float x) {
    union { float f; unsigned int u; } v; v.f = x;
    v.u += 0x7fffu + ((v.u >> 16) & 1u);   // RNE
    return (unsigned short)(v.u >> 16);
}

// ---------------------------------------------------------------------------
// One-shot conversion of all weights (f32->bf16) + h-state init.
// h blobs are STAMPED DWORDS: dword = (bf16<<16) | step_stamp, laid out as
// [tile = (b>>4)*64 + (j>>4)][ (b&15)*16 + (j&15) ], 256 dwords per tile.
// ---------------------------------------------------------------------------
__global__ void conv_all(const float* __restrict__ emb, const float* __restrict__ wih0,
                         const float* __restrict__ whh0, const float* __restrict__ wih1,
                         const float* __restrict__ whh1, const float* __restrict__ wproj,
                         const float* __restrict__ hs,
                         unsigned short* __restrict__ embB, unsigned short* __restrict__ wih0B,
                         unsigned short* __restrict__ whh0B, unsigned short* __restrict__ wih1B,
                         unsigned short* __restrict__ whh1B, unsigned short* __restrict__ wprojB,
                         unsigned int* __restrict__ h0b0, unsigned int* __restrict__ h1b0,
                         float* __restrict__ h0f, float* __restrict__ h1f) {
    int i = (blockIdx.x * 256 + threadIdx.x) * 4;
    const float* src; unsigned short* dst; int off;
    if (i < 32768)         { src = emb;   dst = embB;   off = 0; }
    else if (i < 819200)   { src = wih0;  dst = wih0B;  off = 32768; }
    else if (i < 3964928)  { src = whh0;  dst = whh0B;  off = 819200; }
    else if (i < 7110656)  { src = wih1;  dst = wih1B;  off = 3964928; }
    else if (i < 10256384) { src = whh1;  dst = whh1B;  off = 7110656; }
    else if (i < 10387456) { src = wproj; dst = wprojB; off = 10256384; }
    else                   { src = hs;    dst = nullptr; off = 10387456; }
    int k = i - off;
    float4 v = *(const float4*)(src + k);
    if (dst) {
        dst[k + 0] = f2bf(v.x); dst[k + 1] = f2bf(v.y);
        dst[k + 2] = f2bf(v.z); dst[k + 3] = f2bf(v.w);
    } else {
        int kk = k & 65535;
        unsigned int* hb = (k < 65536) ? h0b0 : h1b0;
        float*        hf = (k < 65536) ? h0f  : h1f;
        int b = kk >> 10, j = kk & 1023;
        int bi = ((b >> 4) * 64 + (j >> 4)) * 256 + (b & 15) * 16 + (j & 15);
        hb[bi + 0] = (unsigned int)f2bf(v.x) << 16;   // stamp 0
        hb[bi + 1] = (unsigned int)f2bf(v.y) << 16;
        hb[bi + 2] = (unsigned int)f2bf(v.z) << 16;
        hb[bi + 3] = (unsigned int)f2bf(v.w) << 16;
        hf[kk + 0] = v.x; hf[kk + 1] = v.y; hf[kk + 2] = v.z; hf[kk + 3] = v.w;
    }
}

// ---------------------------------------------------------------------------
// LDS-staged bf16 MFMA GEMM body (round-9, proven).
// ---------------------------------------------------------------------------
template <int MODE, int KTOT>
__device__ __forceinline__ void gemm_dev(const unsigned short* __restrict__ A,
                                         const unsigned short* __restrict__ Bw,
                                         const float* __restrict__ bias,
                                         float* __restrict__ Cout, int N,
                                         const int* __restrict__ xidx,
                                         const unsigned short* __restrict__ emb,
                                         int row_base, int bx, int by,
                                         unsigned short* smem) {
    const int tid = threadIdx.x;
    const int w = tid >> 6, l = tid & 63;
    const int m0 = bx * 64, n0 = by * 64;
    const int r = l & 15;

    const unsigned short* apt[4];
    const unsigned short* bpt[4];
    int wrA[4], wrB[4];
#pragma unroll
    for (int i = 0; i < 4; ++i) {
        int u = tid + 256 * i;
        int row = u >> 4;
        int ku = u & 15;
        int slot = ku ^ (row & 7);
        if (MODE == 1) {
            int g = row_base + m0 + row;
            apt[i] = emb + (size_t)xidx[(g & 63) * SEQ + (g >> 6)] * KTOT + ku * 8;
        } else {
            apt[i] = A + (size_t)(m0 + row) * KTOT + ku * 8;
        }
        bpt[i] = Bw + (size_t)(n0 + row) * KTOT + ku * 8;
        wrA[i] = row * 128 + slot * 8;
        wrB[i] = 8192 + row * 128 + slot * 8;
    }

    f32x4 acc[4] = {};
    bf16x8 va[4], vb[4];

#pragma unroll
    for (int i = 0; i < 4; ++i) va[i] = *(const bf16x8*)(apt[i]);
#pragma unroll
    for (int i = 0; i < 4; ++i) vb[i] = *(const bf16x8*)(bpt[i]);

    constexpr int NKB = KTOT / 128;
#pragma unroll
    for (int kb = 0; kb < NKB; ++kb) {
#pragma unroll
        for (int i = 0; i < 4; ++i) *(bf16x8*)(smem + wrA[i]) = va[i];
#pragma unroll
        for (int i = 0; i < 4; ++i) *(bf16x8*)(smem + wrB[i]) = vb[i];
        __syncthreads();
        if (kb + 1 < NKB) {
            const int ko = (kb + 1) * 128;
#pragma unroll
            for (int i = 0; i < 4; ++i) va[i] = *(const bf16x8*)(apt[i] + ko);
#pragma unroll
            for (int i = 0; i < 4; ++i) vb[i] = *(const bf16x8*)(bpt[i] + ko);
        }
#pragma unroll
        for (int ks = 0; ks < 4; ++ks) {
            const int slot = (ks * 4 + (l >> 4)) ^ (r & 7);
            bf16x8 a = *(const bf16x8*)(smem + (w * 16 + r) * 128 + slot * 8);
#pragma unroll
            for (int nt = 0; nt < 4; ++nt) {
                bf16x8 b = *(const bf16x8*)(smem + 8192 + (nt * 16 + r) * 128 + slot * 8);
                acc[nt] = __builtin_amdgcn_mfma_f32_16x16x32_bf16(a, b, acc[nt], 0, 0, 0);
            }
        }
        __syncthreads();
    }

    const int la = l & 15, rbase = (l >> 4) * 4;
#pragma unroll
    for (int nt = 0; nt < 4; ++nt) {
        int colg = n0 + nt * 16 + la;
        float bsv = bias[colg];
#pragma unroll
        for (int i = 0; i < 4; ++i) {
            int rowg = m0 + w * 16 + rbase + i;
            float v = acc[nt][i] + bsv;
            if (MODE == 2) {
                int g = row_base + rowg;
                int s = g >> 6, b = g & 63;
                Cout[((size_t)(b * SEQ + s)) * NCLS + colg] = v;
            } else {
                Cout[(size_t)rowg * N + colg] = v;
            }
        }
    }
}

// ---------------------------------------------------------------------------
__global__ __launch_bounds__(256)
void gemm_multi(int na, int nb,
                const int* __restrict__ x, const unsigned short* __restrict__ embB,
                const unsigned short* __restrict__ wih0B, const float* __restrict__ bih0,
                float* __restrict__ giA, int rbA,
                const unsigned short* __restrict__ out0b,
                const unsigned short* __restrict__ wih1B, const float* __restrict__ bih1,
                float* __restrict__ giB,
                const unsigned short* __restrict__ out1b,
                const unsigned short* __restrict__ wprojB, const float* __restrict__ bproj,
                float* __restrict__ logits, int rbP) {
    __shared__ unsigned short smem[16384];   // 32 KB
    int bid = blockIdx.x;
    if (bid < na) {
        gemm_dev<1, EMB>(nullptr, wih0B, bih0, giA, GATES, x, embB, rbA,
                         bid % MX, bid / MX, smem);
    } else if (bid < na + nb) {
        int b = bid - na;
        gemm_dev<0, HID>(out0b, wih1B, bih1, giB, GATES, nullptr, nullptr, 0,
                         b % MX, b / MX, smem);
    } else {
        int b = bid - na - nb;
        gemm_dev<2, HID>(out1b, wprojB, bproj, logits, NCLS, nullptr, nullptr, rbP,
                         b % MX, b / MX, smem);
    }
}

// ---------------------------------------------------------------------------
// Dual-layer persistent GRU chunk kernel — STAMPED-DATA exchange.
// h blob = dword (bf16<<16)|stamp. Producer: 1 coalesced 1KB tile store, no
// drain/flag/barrier. Consumer: load 16x dwordx4, check 64 stamps, retry.
// Correctness: dword atomicity (value+stamp arrive together) + transitive
// data-dependency ordering (a block writes ping(t+2) only after consuming all
// of pong(t+1), whose producers consumed all of ping(t)). No fences anywhere.
// ---------------------------------------------------------------------------
__global__ __launch_bounds__(256, 2)
void gru_dual(int n0, int sb0, int sb1,
              const float* __restrict__ gi0, const unsigned short* __restrict__ wh0,
              const float* __restrict__ bh0, float* __restrict__ h0f,
              unsigned int* __restrict__ h0p, unsigned int* __restrict__ h0q,
              unsigned short* __restrict__ out0,
              const float* __restrict__ gi1, const unsigned short* __restrict__ wh1,
              const float* __restrict__ bh1, float* __restrict__ h1f,
              unsigned int* __restrict__ h1p, unsigned int* __restrict__ h1q,
              unsigned short* __restrict__ out1) {
    __shared__ char smem[35840];          // h tile 32KB @0, sg 3KB @32768
    float* sg = (float*)(smem + 32768);

    const int bid = blockIdx.x;
    const bool L1 = (bid >= n0);
    const int lb = L1 ? bid - n0 : bid;
    const int sbase = L1 ? sb1 : sb0;
    const float* gi = L1 ? gi1 : gi0;
    const unsigned short* whb = L1 ? wh1 : wh0;
    const float* b_hh = L1 ? bh1 : bh0;
    float* h_f = L1 ? h1f : h0f;
    unsigned int* hbuf[2] = {L1 ? h1p : h0p, L1 ? h1q : h0q};
    unsigned short* outseq = L1 ? out1 : out0;

    const int bg = lb >> 6;
    const int jt = lb & 63;
    const int b0 = bg * 16, j0 = jt * 16;
    const int tid = threadIdx.x;
    const int w = tid >> 6, l = tid & 63;

    // ---- w slice into VGPRs (gate waves): 16 rows x 1024 K, 32 x bf16x8 ----
    bf16x8 wreg[32];
    if (w < 3) {
        const unsigned short* wrow = whb + (size_t)(w * HID + j0 + (l & 15)) * HID
                                     + ((l >> 4) * 8);
#pragma unroll
        for (int ks = 0; ks < 32; ++ks) wreg[ks] = *(const bf16x8*)(wrow + ks * 32);
    }

    // ---- own f32 state + biases ----
    const int prow = tid >> 4, pcol = tid & 15;
    const int pb = b0 + prow, pj = j0 + pcol;
    float hp = h_f[(size_t)pb * HID + pj];
    const float bhr = b_hh[pj], bhz = b_hh[HID + pj], bhn = b_hh[2 * HID + pj];

    // consumer decode geometry: unit k of thread covers tile (tid>>2),
    // row rb+(k>>2), cols (k&3)*4..+3
    const int rb = (tid & 3) * 4;
    const int jb2 = (tid >> 2) * 32;     // j0*2 byte base within LDS row

#define CHK(V) ((V[0] ^ sexp) | (V[1] ^ sexp) | (V[2] ^ sexp) | (V[3] ^ sexp))
#define PUT(K, V) do {                                                        \
        int r_ = rb + ((K) >> 2);                                             \
        u32x2 pk_;                                                            \
        pk_[0] = (V[0] >> 16) | (V[1] & 0xffff0000u);                         \
        pk_[1] = (V[2] >> 16) | (V[3] & 0xffff0000u);                         \
        *(u32x2*)(smem + r_ * 2048 +                                          \
                  ((jb2 + ((K) & 3) * 8) ^ ((r_ & 7) << 4))) = pk_;           \
    } while (0)

    for (int t = 0; t < TCH; ++t) {
        const unsigned int* hin = hbuf[t & 1];
        unsigned int* hout = hbuf[(t + 1) & 1];
        const unsigned int sexp = (unsigned int)(sbase + t) & 0xffffu;
        const unsigned int snew = (unsigned int)(sbase + t + 1) & 0xffffu;

        // ---- prefetch this step's gi operands (independent of h) ----
        const float* git = gi + ((size_t)(t * BATCH + pb)) * GATES;
        float gir = git[pj];
        float giz = git[HID + pj];
        float gin = git[2 * HID + pj];

        // ---- poll-load group h blob: 16 x dwordx4, stamps self-validate ----
        const unsigned int* hbase = hin + ((size_t)bg << 14) + (size_t)tid * 64;
        u32x4 u0, u1, u2, u3, u4, u5, u6, u7, u8, u9, u10, u11, u12, u13, u14, u15;
        unsigned int bad;
        do {
            asm volatile(
                "global_load_dwordx4 %0, %16, off sc0 sc1\n\t"
                "global_load_dwordx4 %1, %16, off offset:16 sc0 sc1\n\t"
                "global_load_dwordx4 %2, %16, off offset:32 sc0 sc1\n\t"
                "global_load_dwordx4 %3, %16, off offset:48 sc0 sc1\n\t"
                "global_load_dwordx4 %4, %16, off offset:64 sc0 sc1\n\t"
                "global_load_dwordx4 %5, %16, off offset:80 sc0 sc1\n\t"
                "global_load_dwordx4 %6, %16, off offset:96 sc0 sc1\n\t"
                "global_load_dwordx4 %7, %16, off offset:112 sc0 sc1\n\t"
                "global_load_dwordx4 %8, %16, off offset:128 sc0 sc1\n\t"
                "global_load_dwordx4 %9, %16, off offset:144 sc0 sc1\n\t"
                "global_load_dwordx4 %10, %16, off offset:160 sc0 sc1\n\t"
                "global_load_dwordx4 %11, %16, off offset:176 sc0 sc1\n\t"
                "global_load_dwordx4 %12, %16, off offset:192 sc0 sc1\n\t"
                "global_load_dwordx4 %13, %16, off offset:208 sc0 sc1\n\t"
                "global_load_dwordx4 %14, %16, off offset:224 sc0 sc1\n\t"
                "global_load_dwordx4 %15, %16, off offset:240 sc0 sc1\n\t"
                "s_waitcnt vmcnt(0)"
                : "=&v"(u0), "=&v"(u1), "=&v"(u2), "=&v"(u3),
                  "=&v"(u4), "=&v"(u5), "=&v"(u6), "=&v"(u7),
                  "=&v"(u8), "=&v"(u9), "=&v"(u10), "=&v"(u11),
                  "=&v"(u12), "=&v"(u13), "=&v"(u14), "=&v"(u15)
                : "v"(hbase)
                : "memory");
            bad = CHK(u0) | CHK(u1) | CHK(u2) | CHK(u3) |
                  CHK(u4) | CHK(u5) | CHK(u6) | CHK(u7) |
                  CHK(u8) | CHK(u9) | CHK(u10) | CHK(u11) |
                  CHK(u12) | CHK(u13) | CHK(u14) | CHK(u15);
        } while (!__all((bad & 0xffffu) == 0));

        PUT(0, u0);  PUT(1, u1);  PUT(2, u2);  PUT(3, u3);
        PUT(4, u4);  PUT(5, u5);  PUT(6, u6);  PUT(7, u7);
        PUT(8, u8);  PUT(9, u9);  PUT(10, u10); PUT(11, u11);
        PUT(12, u12); PUT(13, u13); PUT(14, u14); PUT(15, u15);
        __syncthreads();

        if (w < 3) {
            const int r = l & 15;
            const int sw = (r & 7) << 4;
            const int kq = (l >> 4) * 16;
            const int hbyte = r * 2048;
            f32x4 acc = {};
#pragma unroll
            for (int ks = 0; ks < 32; ++ks) {
                bf16x8 a = *(const bf16x8*)(smem + hbyte + ((ks * 64 + kq) ^ sw));
                acc = __builtin_amdgcn_mfma_f32_16x16x32_bf16(a, wreg[ks], acc, 0, 0, 0);
            }
            const int col = l & 15, rbase = (l >> 4) * 4;
#pragma unroll
            for (int i = 0; i < 4; ++i) sg[w * 256 + (rbase + i) * 16 + col] = acc[i];
        }
        __syncthreads();

        // ---- pointwise (all 256 threads, own (b,j)) ----
        float ghr = sg[0 * 256 + tid] + bhr;
        float ghz = sg[1 * 256 + tid] + bhz;
        float ghn = sg[2 * 256 + tid] + bhn;
        float rr2 = 1.f / (1.f + __expf(-(gir + ghr)));
        float zz = 1.f / (1.f + __expf(-(giz + ghz)));
        float nn = tanhf(gin + rr2 * ghn);
        hp = (1.f - zz) * nn + zz * hp;
        unsigned short hb = f2bf(hp);
        outseq[((size_t)(t * BATCH + pb)) * HID + pj] = hb;

        // ---- stamped dword publish: fire-and-forget, no drain ----
        unsigned int val = ((unsigned int)hb << 16) | snew;
        asm volatile("global_store_dword %0, %1, off sc0 sc1"
                     :: "v"(hout + (size_t)(bg * 64 + jt) * 256 + tid), "v"(val)
                     : "memory");
    }

    h_f[(size_t)pb * HID + pj] = hp;
#undef CHK
#undef PUT
}

// ---------------------------------------------------------------------------
extern "C" void kernel_launch(void* const* d_in, const int* in_sizes, int n_in,
                              void* d_out, int out_size, void* d_ws, size_t ws_size,
                              hipStream_t stream) {
    const int*   x      = (const int*)d_in[0];
    const float* hs     = (const float*)d_in[1];
    const float* emb    = (const float*)d_in[2];
    const float* w_ih0  = (const float*)d_in[3];
    const float* w_hh0  = (const float*)d_in[4];
    const float* b_ih0  = (const float*)d_in[5];
    const float* b_hh0  = (const float*)d_in[6];
    const float* w_ih1  = (const float*)d_in[7];
    const float* w_hh1  = (const float*)d_in[8];
    const float* b_ih1  = (const float*)d_in[9];
    const float* b_hh1  = (const float*)d_in[10];
    const float* w_proj = (const float*)d_in[11];
    const float* b_proj = (const float*)d_in[12];

    float* logits = (float*)d_out;                       // [B*S, 128] f32
    float* hT     = logits + (size_t)SEQ * BATCH * NCLS; // [2, 64, 1024] f32

    // ---- workspace layout (~55 MB) ----
    char* p = (char*)d_ws;
    float* giA = (float*)p;                     p += (size_t)ROWS * GATES * 4;   // 12.6 MB
    float* giB = (float*)p;                     p += (size_t)ROWS * GATES * 4;   // 12.6 MB
    float* h0f = (float*)p;                     p += 65536 * 4;
    float* h1f = (float*)p;                     p += 65536 * 4;
    unsigned int* h0b0 = (unsigned int*)p;      p += 65536 * 4;   // stamped blobs
    unsigned int* h0b1 = (unsigned int*)p;      p += 65536 * 4;
    unsigned int* h1b0 = (unsigned int*)p;      p += 65536 * 4;
    unsigned int* h1b1 = (unsigned int*)p;      p += 65536 * 4;
    unsigned short* out0b = (unsigned short*)p; p += (size_t)ROWS * HID * 2;     // 2.1 MB
    unsigned short* out1b[2];
    out1b[0] = (unsigned short*)p;              p += (size_t)ROWS * HID * 2;     // 2.1 MB
    out1b[1] = (unsigned short*)p;              p += (size_t)ROWS * HID * 2;     // 2.1 MB
    unsigned short* embB  = (unsigned short*)p; p += (size_t)NCLS * EMB * 2;
    unsigned short* wih0B = (unsigned short*)p; p += (size_t)GATES * EMB * 2;
    unsigned short* whh0B = (unsigned short*)p; p += (size_t)GATES * HID * 2;
    unsigned short* wih1B = (unsigned short*)p; p += (size_t)GATES * HID * 2;
    unsigned short* whh1B = (unsigned short*)p; p += (size_t)GATES * HID * 2;
    unsigned short* wprojB = (unsigned short*)p; p += (size_t)NCLS * HID * 2;

    // ---- one launch: all weight conversions + h-state init ----
    conv_all<<<10272, 256, 0, stream>>>(emb, w_ih0, w_hh0, w_ih1, w_hh1, w_proj, hs,
                                        embB, wih0B, whh0B, wih1B, whh1B, wprojB,
                                        h0b0, h1b0, h0f, h1f);

    // ---- software-pipelined chunk loop: 2 launches per chunk ----
    for (int c = 0; c < NCH; ++c) {
        int na = 768;
        int nb = (c >= 1) ? 768 : 0;
        int np = (c >= 2) ? 32 : 0;
        gemm_multi<<<na + nb + np, 256, 0, stream>>>(na, nb,
            x, embB, wih0B, b_ih0, giA, c * ROWS,
            out0b, wih1B, b_ih1, giB,
            out1b[(c - 2) & 1], wprojB, b_proj, logits, (c >= 2) ? (c - 2) * ROWS : 0);

        int grid = (c >= 1) ? 512 : 256;
        int c1 = (c >= 1) ? c - 1 : 0;
        gru_dual<<<grid, 256, 0, stream>>>(256, c * TCH, c1 * TCH,
            giA, whh0B, b_hh0, h0f, h0b0, h0b1, out0b,
            giB, whh1B, b_hh1, h1f, h1b0, h1b1, out1b[c1 & 1]);
    }

    // ---- pipeline tail: gi1(15)+proj(14), gru1(15), proj(15) ----
    gemm_multi<<<768 + 32, 256, 0, stream>>>(0, 768,
        x, embB, wih0B, b_ih0, giA, 0,
        out0b, wih1B, b_ih1, giB,
        out1b[0], wprojB, b_proj, logits, 14 * ROWS);

    gru_dual<<<256, 256, 0, stream>>>(0, 0, 15 * TCH,
        giA, whh0B, b_hh0, h0f, h0b0, h0b1, out0b,
        giB, whh1B, b_hh1, h1f, h1b0, h1b1, out1b[1]);

    gemm_multi<<<32, 256, 0, stream>>>(0, 0,
        x, embB, wih0B, b_ih0, giA, 0,
        out0b, wih1B, b_ih1, giB,
        out1b[1], wprojB, b_proj, logits, 15 * ROWS);

    hipMemcpyAsync(hT, h0f, 65536 * 4, hipMemcpyDeviceToDevice, stream);
    hipMemcpyAsync(hT + 65536, h1f, 65536 * 4, hipMemcpyDeviceToDevice, stream);
}

// Round 13
// 4884.794 us; speedup vs baseline: 1.2771x; 1.2771x over previous
//
#include <hip/hip_runtime.h>
#include <hip/hip_bf16.h>

#define SEQ    256
#define BATCH  64
#define EMB    256
#define HID    1024
#define GATES  3072   // 3*HID
#define NCLS   128
#define TCH    16                 // time chunk
#define ROWS   (TCH * BATCH)      // 1024 rows per chunk
#define NCH    (SEQ / TCH)        // 16 chunks
#define MX     (ROWS / 64)        // 16 m-tiles per GEMM

typedef __attribute__((ext_vector_type(8))) short bf16x8;
typedef __attribute__((ext_vector_type(4))) float f32x4;
typedef __attribute__((ext_vector_type(4))) unsigned int u32x4;
typedef __attribute__((ext_vector_type(2))) unsigned int u32x2;

__device__ inline unsigned short f2bf(float x) {
    union { float f; unsigned int u; } v; v.f = x;
    v.u += 0x7fffu + ((v.u >> 16) & 1u);   // RNE
    return (unsigned short)(v.u >> 16);
}

// ---------------------------------------------------------------------------
// One-shot conversion of all weights (f32->bf16) + h-state init.
// h blobs are STAMPED DWORDS: dword = (bf16<<16) | step_stamp, laid out as
// [tile = (b>>4)*64 + (j>>4)][ (b&15)*16 + (j&15) ], 256 dwords per tile.
// ---------------------------------------------------------------------------
__global__ void conv_all(const float* __restrict__ emb, const float* __restrict__ wih0,
                         const float* __restrict__ whh0, const float* __restrict__ wih1,
                         const float* __restrict__ whh1, const float* __restrict__ wproj,
                         const float* __restrict__ hs,
                         unsigned short* __restrict__ embB, unsigned short* __restrict__ wih0B,
                         unsigned short* __restrict__ whh0B, unsigned short* __restrict__ wih1B,
                         unsigned short* __restrict__ whh1B, unsigned short* __restrict__ wprojB,
                         unsigned int* __restrict__ h0b0, unsigned int* __restrict__ h1b0,
                         float* __restrict__ h0f, float* __restrict__ h1f) {
    int i = (blockIdx.x * 256 + threadIdx.x) * 4;
    const float* src; unsigned short* dst; int off;
    if (i < 32768)         { src = emb;   dst = embB;   off = 0; }
    else if (i < 819200)   { src = wih0;  dst = wih0B;  off = 32768; }
    else if (i < 3964928)  { src = whh0;  dst = whh0B;  off = 819200; }
    else if (i < 7110656)  { src = wih1;  dst = wih1B;  off = 3964928; }
    else if (i < 10256384) { src = whh1;  dst = whh1B;  off = 7110656; }
    else if (i < 10387456) { src = wproj; dst = wprojB; off = 10256384; }
    else                   { src = hs;    dst = nullptr; off = 10387456; }
    int k = i - off;
    float4 v = *(const float4*)(src + k);
    if (dst) {
        dst[k + 0] = f2bf(v.x); dst[k + 1] = f2bf(v.y);
        dst[k + 2] = f2bf(v.z); dst[k + 3] = f2bf(v.w);
    } else {
        int kk = k & 65535;
        unsigned int* hb = (k < 65536) ? h0b0 : h1b0;
        float*        hf = (k < 65536) ? h0f  : h1f;
        int b = kk >> 10, j = kk & 1023;
        int bi = ((b >> 4) * 64 + (j >> 4)) * 256 + (b & 15) * 16 + (j & 15);
        hb[bi + 0] = (unsigned int)f2bf(v.x) << 16;   // stamp 0
        hb[bi + 1] = (unsigned int)f2bf(v.y) << 16;
        hb[bi + 2] = (unsigned int)f2bf(v.z) << 16;
        hb[bi + 3] = (unsigned int)f2bf(v.w) << 16;
        hf[kk + 0] = v.x; hf[kk + 1] = v.y; hf[kk + 2] = v.z; hf[kk + 3] = v.w;
    }
}

// ---------------------------------------------------------------------------
// LDS-staged bf16 MFMA GEMM body (round-9, proven).
// ---------------------------------------------------------------------------
template <int MODE, int KTOT>
__device__ __forceinline__ void gemm_dev(const unsigned short* __restrict__ A,
                                         const unsigned short* __restrict__ Bw,
                                         const float* __restrict__ bias,
                                         float* __restrict__ Cout, int N,
                                         const int* __restrict__ xidx,
                                         const unsigned short* __restrict__ emb,
                                         int row_base, int bx, int by,
                                         unsigned short* smem) {
    const int tid = threadIdx.x;
    const int w = tid >> 6, l = tid & 63;
    const int m0 = bx * 64, n0 = by * 64;
    const int r = l & 15;

    const unsigned short* apt[4];
    const unsigned short* bpt[4];
    int wrA[4], wrB[4];
#pragma unroll
    for (int i = 0; i < 4; ++i) {
        int u = tid + 256 * i;
        int row = u >> 4;
        int ku = u & 15;
        int slot = ku ^ (row & 7);
        if (MODE == 1) {
            int g = row_base + m0 + row;
            apt[i] = emb + (size_t)xidx[(g & 63) * SEQ + (g >> 6)] * KTOT + ku * 8;
        } else {
            apt[i] = A + (size_t)(m0 + row) * KTOT + ku * 8;
        }
        bpt[i] = Bw + (size_t)(n0 + row) * KTOT + ku * 8;
        wrA[i] = row * 128 + slot * 8;
        wrB[i] = 8192 + row * 128 + slot * 8;
    }

    f32x4 acc[4] = {};
    bf16x8 va[4], vb[4];

#pragma unroll
    for (int i = 0; i < 4; ++i) va[i] = *(const bf16x8*)(apt[i]);
#pragma unroll
    for (int i = 0; i < 4; ++i) vb[i] = *(const bf16x8*)(bpt[i]);

    constexpr int NKB = KTOT / 128;
#pragma unroll
    for (int kb = 0; kb < NKB; ++kb) {
#pragma unroll
        for (int i = 0; i < 4; ++i) *(bf16x8*)(smem + wrA[i]) = va[i];
#pragma unroll
        for (int i = 0; i < 4; ++i) *(bf16x8*)(smem + wrB[i]) = vb[i];
        __syncthreads();
        if (kb + 1 < NKB) {
            const int ko = (kb + 1) * 128;
#pragma unroll
            for (int i = 0; i < 4; ++i) va[i] = *(const bf16x8*)(apt[i] + ko);
#pragma unroll
            for (int i = 0; i < 4; ++i) vb[i] = *(const bf16x8*)(bpt[i] + ko);
        }
#pragma unroll
        for (int ks = 0; ks < 4; ++ks) {
            const int slot = (ks * 4 + (l >> 4)) ^ (r & 7);
            bf16x8 a = *(const bf16x8*)(smem + (w * 16 + r) * 128 + slot * 8);
#pragma unroll
            for (int nt = 0; nt < 4; ++nt) {
                bf16x8 b = *(const bf16x8*)(smem + 8192 + (nt * 16 + r) * 128 + slot * 8);
                acc[nt] = __builtin_amdgcn_mfma_f32_16x16x32_bf16(a, b, acc[nt], 0, 0, 0);
            }
        }
        __syncthreads();
    }

    const int la = l & 15, rbase = (l >> 4) * 4;
#pragma unroll
    for (int nt = 0; nt < 4; ++nt) {
        int colg = n0 + nt * 16 + la;
        float bsv = bias[colg];
#pragma unroll
        for (int i = 0; i < 4; ++i) {
            int rowg = m0 + w * 16 + rbase + i;
            float v = acc[nt][i] + bsv;
            if (MODE == 2) {
                int g = row_base + rowg;
                int s = g >> 6, b = g & 63;
                Cout[((size_t)(b * SEQ + s)) * NCLS + colg] = v;
            } else {
                Cout[(size_t)rowg * N + colg] = v;
            }
        }
    }
}

// ---------------------------------------------------------------------------
__global__ __launch_bounds__(256)
void gemm_multi(int na, int nb,
                const int* __restrict__ x, const unsigned short* __restrict__ embB,
                const unsigned short* __restrict__ wih0B, const float* __restrict__ bih0,
                float* __restrict__ giA, int rbA,
                const unsigned short* __restrict__ out0b,
                const unsigned short* __restrict__ wih1B, const float* __restrict__ bih1,
                float* __restrict__ giB,
                const unsigned short* __restrict__ out1b,
                const unsigned short* __restrict__ wprojB, const float* __restrict__ bproj,
                float* __restrict__ logits, int rbP) {
    __shared__ unsigned short smem[16384];   // 32 KB
    int bid = blockIdx.x;
    if (bid < na) {
        gemm_dev<1, EMB>(nullptr, wih0B, bih0, giA, GATES, x, embB, rbA,
                         bid % MX, bid / MX, smem);
    } else if (bid < na + nb) {
        int b = bid - na;
        gemm_dev<0, HID>(out0b, wih1B, bih1, giB, GATES, nullptr, nullptr, 0,
                         b % MX, b / MX, smem);
    } else {
        int b = bid - na - nb;
        gemm_dev<2, HID>(out1b, wprojB, bproj, logits, NCLS, nullptr, nullptr, rbP,
                         b % MX, b / MX, smem);
    }
}

// ---------------------------------------------------------------------------
// Dual-layer persistent GRU chunk kernel — HYBRID exchange:
//  producer: per-thread STAMPED dword store (no drain, no pack), then flag.
//  consumer: wait on FLAG array (cheap 64-line poll, R11-proven), then load
//            blob once; stamps backstop the store-arrival race (rare retry
//            with s_sleep backoff — bounded, unlike R12's spin).
// ---------------------------------------------------------------------------
__global__ __launch_bounds__(256, 2)
void gru_dual(int n0, int sb0, int sb1,
              const float* __restrict__ gi0, const unsigned short* __restrict__ wh0,
              const float* __restrict__ bh0, float* __restrict__ h0f,
              unsigned int* __restrict__ h0p, unsigned int* __restrict__ h0q,
              unsigned short* __restrict__ out0, int* __restrict__ bar0,
              const float* __restrict__ gi1, const unsigned short* __restrict__ wh1,
              const float* __restrict__ bh1, float* __restrict__ h1f,
              unsigned int* __restrict__ h1p, unsigned int* __restrict__ h1q,
              unsigned short* __restrict__ out1, int* __restrict__ bar1) {
    __shared__ char smem[35840];          // h tile 32KB @0, sg 3KB @32768
    float* sg = (float*)(smem + 32768);

    const int bid = blockIdx.x;
    const bool L1 = (bid >= n0);
    const int lb = L1 ? bid - n0 : bid;
    const int sbase = L1 ? sb1 : sb0;
    const float* gi = L1 ? gi1 : gi0;
    const unsigned short* whb = L1 ? wh1 : wh0;
    const float* b_hh = L1 ? bh1 : bh0;
    float* h_f = L1 ? h1f : h0f;
    unsigned int* hbuf[2] = {L1 ? h1p : h0p, L1 ? h1q : h0q};
    unsigned short* outseq = L1 ? out1 : out0;
    int* bar = L1 ? bar1 : bar0;

    const int bg = lb >> 6;
    const int jt = lb & 63;
    const int b0 = bg * 16, j0 = jt * 16;
    const int tid = threadIdx.x;
    const int w = tid >> 6, l = tid & 63;

    // ---- w slice into VGPRs (gate waves): 16 rows x 1024 K, 32 x bf16x8 ----
    bf16x8 wreg[32];
    if (w < 3) {
        const unsigned short* wrow = whb + (size_t)(w * HID + j0 + (l & 15)) * HID
                                     + ((l >> 4) * 8);
#pragma unroll
        for (int ks = 0; ks < 32; ++ks) wreg[ks] = *(const bf16x8*)(wrow + ks * 32);
    }

    // ---- own f32 state + biases ----
    const int prow = tid >> 4, pcol = tid & 15;
    const int pb = b0 + prow, pj = j0 + pcol;
    float hp = h_f[(size_t)pb * HID + pj];
    const float bhr = b_hh[pj], bhz = b_hh[HID + pj], bhn = b_hh[2 * HID + pj];

    // consumer decode geometry: unit k of thread covers tile (tid>>2),
    // row rb+(k>>2), cols (k&3)*4..+3
    const int rb = (tid & 3) * 4;
    const int jb2 = (tid >> 2) * 32;     // j-tile byte base within LDS row

#define CHK(V) ((V[0] ^ sexp) | (V[1] ^ sexp) | (V[2] ^ sexp) | (V[3] ^ sexp))
#define PUT(K, V) do {                                                        \
        int r_ = rb + ((K) >> 2);                                             \
        u32x2 pk_;                                                            \
        pk_[0] = (V[0] >> 16) | (V[1] & 0xffff0000u);                         \
        pk_[1] = (V[2] >> 16) | (V[3] & 0xffff0000u);                         \
        *(u32x2*)(smem + r_ * 2048 +                                          \
                  ((jb2 + ((K) & 3) * 8) ^ ((r_ & 7) << 4))) = pk_;           \
    } while (0)

    for (int t = 0; t < TCH; ++t) {
        const unsigned int* hin = hbuf[t & 1];
        unsigned int* hout = hbuf[(t + 1) & 1];
        const unsigned int sexp = (unsigned int)(sbase + t) & 0xffffu;
        const unsigned int snew = (unsigned int)(sbase + t + 1) & 0xffffu;

        // ---- prefetch this step's gi operands (independent of h) ----
        const float* git = gi + ((size_t)(t * BATCH + pb)) * GATES;
        float gir = git[pj];
        float giz = git[HID + pj];
        float gin = git[2 * HID + pj];

        // ---- load group h blob once; stamps validate; rare backoff retry ----
        const unsigned int* hbase = hin + ((size_t)bg << 14) + (size_t)tid * 64;
        u32x4 u0, u1, u2, u3, u4, u5, u6, u7, u8, u9, u10, u11, u12, u13, u14, u15;
        for (;;) {
            asm volatile(
                "global_load_dwordx4 %0, %16, off sc0 sc1\n\t"
                "global_load_dwordx4 %1, %16, off offset:16 sc0 sc1\n\t"
                "global_load_dwordx4 %2, %16, off offset:32 sc0 sc1\n\t"
                "global_load_dwordx4 %3, %16, off offset:48 sc0 sc1\n\t"
                "global_load_dwordx4 %4, %16, off offset:64 sc0 sc1\n\t"
                "global_load_dwordx4 %5, %16, off offset:80 sc0 sc1\n\t"
                "global_load_dwordx4 %6, %16, off offset:96 sc0 sc1\n\t"
                "global_load_dwordx4 %7, %16, off offset:112 sc0 sc1\n\t"
                "global_load_dwordx4 %8, %16, off offset:128 sc0 sc1\n\t"
                "global_load_dwordx4 %9, %16, off offset:144 sc0 sc1\n\t"
                "global_load_dwordx4 %10, %16, off offset:160 sc0 sc1\n\t"
                "global_load_dwordx4 %11, %16, off offset:176 sc0 sc1\n\t"
                "global_load_dwordx4 %12, %16, off offset:192 sc0 sc1\n\t"
                "global_load_dwordx4 %13, %16, off offset:208 sc0 sc1\n\t"
                "global_load_dwordx4 %14, %16, off offset:224 sc0 sc1\n\t"
                "global_load_dwordx4 %15, %16, off offset:240 sc0 sc1\n\t"
                "s_waitcnt vmcnt(0)"
                : "=&v"(u0), "=&v"(u1), "=&v"(u2), "=&v"(u3),
                  "=&v"(u4), "=&v"(u5), "=&v"(u6), "=&v"(u7),
                  "=&v"(u8), "=&v"(u9), "=&v"(u10), "=&v"(u11),
                  "=&v"(u12), "=&v"(u13), "=&v"(u14), "=&v"(u15)
                : "v"(hbase)
                : "memory");
            unsigned int bad = CHK(u0) | CHK(u1) | CHK(u2) | CHK(u3) |
                               CHK(u4) | CHK(u5) | CHK(u6) | CHK(u7) |
                               CHK(u8) | CHK(u9) | CHK(u10) | CHK(u11) |
                               CHK(u12) | CHK(u13) | CHK(u14) | CHK(u15);
            if (__all((bad & 0xffffu) == 0)) break;
            __builtin_amdgcn_s_sleep(2);    // rare: flag outran a store
        }

        PUT(0, u0);  PUT(1, u1);  PUT(2, u2);  PUT(3, u3);
        PUT(4, u4);  PUT(5, u5);  PUT(6, u6);  PUT(7, u7);
        PUT(8, u8);  PUT(9, u9);  PUT(10, u10); PUT(11, u11);
        PUT(12, u12); PUT(13, u13); PUT(14, u14); PUT(15, u15);
        __syncthreads();

        if (w < 3) {
            const int r = l & 15;
            const int sw = (r & 7) << 4;
            const int kq = (l >> 4) * 16;
            const int hbyte = r * 2048;
            f32x4 acc = {};
#pragma unroll
            for (int ks = 0; ks < 32; ++ks) {
                bf16x8 a = *(const bf16x8*)(smem + hbyte + ((ks * 64 + kq) ^ sw));
                acc = __builtin_amdgcn_mfma_f32_16x16x32_bf16(a, wreg[ks], acc, 0, 0, 0);
            }
            const int col = l & 15, rbase = (l >> 4) * 4;
#pragma unroll
            for (int i = 0; i < 4; ++i) sg[w * 256 + (rbase + i) * 16 + col] = acc[i];
        }
        __syncthreads();

        // ---- pointwise (all 256 threads, own (b,j)) ----
        float ghr = sg[0 * 256 + tid] + bhr;
        float ghz = sg[1 * 256 + tid] + bhz;
        float ghn = sg[2 * 256 + tid] + bhn;
        float rr2 = 1.f / (1.f + __expf(-(gir + ghr)));
        float zz = 1.f / (1.f + __expf(-(giz + ghz)));
        float nn = tanhf(gin + rr2 * ghn);
        hp = (1.f - zz) * nn + zz * hp;
        unsigned short hb = f2bf(hp);
        outseq[((size_t)(t * BATCH + pb)) * HID + pj] = hb;

        // ---- stamped dword publish: fire-and-forget, no drain ----
        unsigned int val = ((unsigned int)hb << 16) | snew;
        asm volatile("global_store_dword %0, %1, off sc0 sc1"
                     :: "v"(hout + (size_t)(bg * 64 + jt) * 256 + tid), "v"(val)
                     : "memory");

        if (t < TCH - 1) {
            // ---- flag barrier (R11): readiness hint, stamps are backstop ----
            __syncthreads();          // all threads issued their stores
            if (tid == 0) {
                __hip_atomic_store(bar + (((bg << 6) | jt) << 4), t + 1,
                                   __ATOMIC_RELAXED, __HIP_MEMORY_SCOPE_AGENT);
            }
            if (tid < 64) {
                const int* f = bar + (((bg << 6) | tid) << 4);
                while (!__all(__hip_atomic_load(f, __ATOMIC_RELAXED,
                                                __HIP_MEMORY_SCOPE_AGENT) > t)) {
                    __builtin_amdgcn_s_sleep(1);
                }
            }
            __syncthreads();
        }
    }

    h_f[(size_t)pb * HID + pj] = hp;
#undef CHK
#undef PUT
}

// ---------------------------------------------------------------------------
extern "C" void kernel_launch(void* const* d_in, const int* in_sizes, int n_in,
                              void* d_out, int out_size, void* d_ws, size_t ws_size,
                              hipStream_t stream) {
    const int*   x      = (const int*)d_in[0];
    const float* hs     = (const float*)d_in[1];
    const float* emb    = (const float*)d_in[2];
    const float* w_ih0  = (const float*)d_in[3];
    const float* w_hh0  = (const float*)d_in[4];
    const float* b_ih0  = (const float*)d_in[5];
    const float* b_hh0  = (const float*)d_in[6];
    const float* w_ih1  = (const float*)d_in[7];
    const float* w_hh1  = (const float*)d_in[8];
    const float* b_ih1  = (const float*)d_in[9];
    const float* b_hh1  = (const float*)d_in[10];
    const float* w_proj = (const float*)d_in[11];
    const float* b_proj = (const float*)d_in[12];

    float* logits = (float*)d_out;                       // [B*S, 128] f32
    float* hT     = logits + (size_t)SEQ * BATCH * NCLS; // [2, 64, 1024] f32

    // ---- workspace layout (~56 MB) ----
    char* p = (char*)d_ws;
    float* giA = (float*)p;                     p += (size_t)ROWS * GATES * 4;   // 12.6 MB
    float* giB = (float*)p;                     p += (size_t)ROWS * GATES * 4;   // 12.6 MB
    float* h0f = (float*)p;                     p += 65536 * 4;
    float* h1f = (float*)p;                     p += 65536 * 4;
    unsigned int* h0b0 = (unsigned int*)p;      p += 65536 * 4;   // stamped blobs
    unsigned int* h0b1 = (unsigned int*)p;      p += 65536 * 4;
    unsigned int* h1b0 = (unsigned int*)p;      p += 65536 * 4;
    unsigned int* h1b1 = (unsigned int*)p;      p += 65536 * 4;
    unsigned short* out0b = (unsigned short*)p; p += (size_t)ROWS * HID * 2;     // 2.1 MB
    unsigned short* out1b[2];
    out1b[0] = (unsigned short*)p;              p += (size_t)ROWS * HID * 2;     // 2.1 MB
    out1b[1] = (unsigned short*)p;              p += (size_t)ROWS * HID * 2;     // 2.1 MB
    unsigned short* embB  = (unsigned short*)p; p += (size_t)NCLS * EMB * 2;
    unsigned short* wih0B = (unsigned short*)p; p += (size_t)GATES * EMB * 2;
    unsigned short* whh0B = (unsigned short*)p; p += (size_t)GATES * HID * 2;
    unsigned short* wih1B = (unsigned short*)p; p += (size_t)GATES * HID * 2;
    unsigned short* whh1B = (unsigned short*)p; p += (size_t)GATES * HID * 2;
    unsigned short* wprojB = (unsigned short*)p; p += (size_t)NCLS * HID * 2;
    int* bar = (int*)p;                         p += (size_t)32 * 4096 * 4;      // 512 KB flags

    // ---- flag regions: reset every call (graph-replay safe) ----
    hipMemsetAsync(bar, 0, (size_t)32 * 4096 * 4, stream);

    // ---- one launch: all weight conversions + h-state init ----
    conv_all<<<10272, 256, 0, stream>>>(emb, w_ih0, w_hh0, w_ih1, w_hh1, w_proj, hs,
                                        embB, wih0B, whh0B, wih1B, whh1B, wprojB,
                                        h0b0, h1b0, h0f, h1f);

    // ---- software-pipelined chunk loop: 2 launches per chunk ----
    for (int c = 0; c < NCH; ++c) {
        int na = 768;
        int nb = (c >= 1) ? 768 : 0;
        int np = (c >= 2) ? 32 : 0;
        gemm_multi<<<na + nb + np, 256, 0, stream>>>(na, nb,
            x, embB, wih0B, b_ih0, giA, c * ROWS,
            out0b, wih1B, b_ih1, giB,
            out1b[(c - 2) & 1], wprojB, b_proj, logits, (c >= 2) ? (c - 2) * ROWS : 0);

        int grid = (c >= 1) ? 512 : 256;
        int c1 = (c >= 1) ? c - 1 : 0;
        gru_dual<<<grid, 256, 0, stream>>>(256, c * TCH, c1 * TCH,
            giA, whh0B, b_hh0, h0f, h0b0, h0b1, out0b, bar + (size_t)c * 4096,
            giB, whh1B, b_hh1, h1f, h1b0, h1b1, out1b[c1 & 1],
            bar + (size_t)(16 + c1) * 4096);
    }

    // ---- pipeline tail: gi1(15)+proj(14), gru1(15), proj(15) ----
    gemm_multi<<<768 + 32, 256, 0, stream>>>(0, 768,
        x, embB, wih0B, b_ih0, giA, 0,
        out0b, wih1B, b_ih1, giB,
        out1b[0], wprojB, b_proj, logits, 14 * ROWS);

    gru_dual<<<256, 256, 0, stream>>>(0, 0, 15 * TCH,
        giA, whh0B, b_hh0, h0f, h0b0, h0b1, out0b, bar,
        giB, whh1B, b_hh1, h1f, h1b0, h1b1, out1b[1],
        bar + (size_t)31 * 4096);

    gemm_multi<<<32, 256, 0, stream>>>(0, 0,
        x, embB, wih0B, b_ih0, giA, 0,
        out0b, wih1B, b_ih1, giB,
        out1b[1], wprojB, b_proj, logits, 15 * ROWS);

    hipMemcpyAsync(hT, h0f, 65536 * 4, hipMemcpyDeviceToDevice, stream);
    hipMemcpyAsync(hT + 65536, h1f, 65536 * 4, hipMemcpyDeviceToDevice, stream);
}

// Round 14
// 1525.525 us; speedup vs baseline: 4.0893x; 3.2020x over previous
//
#include <hip/hip_runtime.h>
#include <hip/hip_bf16.h>

#define SEQ    256
#define BATCH  64
#define EMB    256
#define HID    1024
#define GATES  3072   // 3*HID
#define NCLS   128
#define TCH    16                 // time chunk
#define ROWS   (TCH * BATCH)      // 1024 rows per chunk
#define NCH    (SEQ / TCH)        // 16 chunks
#define MX     (ROWS / 64)        // 16 m-tiles per GEMM

typedef __attribute__((ext_vector_type(8))) short bf16x8;
typedef __attribute__((ext_vector_type(4))) float f32x4;

__device__ inline unsigned short f2bf(float x) {
    union { float f; unsigned int u; } v; v.f = x;
    v.u += 0x7fffu + ((v.u >> 16) & 1u);   // RNE
    return (unsigned short)(v.u >> 16);
}

// ---------------------------------------------------------------------------
// One-shot conversion of all weights (f32->bf16) + h-state init.
// h bf16 ping buffer uses BLOB layout: [(b>>4)*64+(j>>4)]*256 + (b&15)*16+(j&15)
// (R11-proven).
// ---------------------------------------------------------------------------
__global__ void conv_all(const float* __restrict__ emb, const float* __restrict__ wih0,
                         const float* __restrict__ whh0, const float* __restrict__ wih1,
                         const float* __restrict__ whh1, const float* __restrict__ wproj,
                         const float* __restrict__ hs,
                         unsigned short* __restrict__ embB, unsigned short* __restrict__ wih0B,
                         unsigned short* __restrict__ whh0B, unsigned short* __restrict__ wih1B,
                         unsigned short* __restrict__ whh1B, unsigned short* __restrict__ wprojB,
                         unsigned short* __restrict__ h0b0, unsigned short* __restrict__ h1b0,
                         float* __restrict__ h0f, float* __restrict__ h1f) {
    int i = (blockIdx.x * 256 + threadIdx.x) * 4;
    const float* src; unsigned short* dst; int off;
    if (i < 32768)         { src = emb;   dst = embB;   off = 0; }
    else if (i < 819200)   { src = wih0;  dst = wih0B;  off = 32768; }
    else if (i < 3964928)  { src = whh0;  dst = whh0B;  off = 819200; }
    else if (i < 7110656)  { src = wih1;  dst = wih1B;  off = 3964928; }
    else if (i < 10256384) { src = whh1;  dst = whh1B;  off = 7110656; }
    else if (i < 10387456) { src = wproj; dst = wprojB; off = 10256384; }
    else                   { src = hs;    dst = nullptr; off = 10387456; }
    int k = i - off;
    float4 v = *(const float4*)(src + k);
    if (dst) {
        dst[k + 0] = f2bf(v.x); dst[k + 1] = f2bf(v.y);
        dst[k + 2] = f2bf(v.z); dst[k + 3] = f2bf(v.w);
    } else {
        int kk = k & 65535;
        unsigned short* hb = (k < 65536) ? h0b0 : h1b0;
        float*          hf = (k < 65536) ? h0f  : h1f;
        int b = kk >> 10, j = kk & 1023;
        int bi = ((b >> 4) * 64 + (j >> 4)) * 256 + (b & 15) * 16 + (j & 15);
        hb[bi + 0] = f2bf(v.x); hb[bi + 1] = f2bf(v.y);
        hb[bi + 2] = f2bf(v.z); hb[bi + 3] = f2bf(v.w);
        hf[kk + 0] = v.x; hf[kk + 1] = v.y; hf[kk + 2] = v.z; hf[kk + 3] = v.w;
    }
}

// ---------------------------------------------------------------------------
// LDS-staged bf16 MFMA GEMM body (round-9, proven).
// ---------------------------------------------------------------------------
template <int MODE, int KTOT>
__device__ __forceinline__ void gemm_dev(const unsigned short* __restrict__ A,
                                         const unsigned short* __restrict__ Bw,
                                         const float* __restrict__ bias,
                                         float* __restrict__ Cout, int N,
                                         const int* __restrict__ xidx,
                                         const unsigned short* __restrict__ emb,
                                         int row_base, int bx, int by,
                                         unsigned short* smem) {
    const int tid = threadIdx.x;
    const int w = tid >> 6, l = tid & 63;
    const int m0 = bx * 64, n0 = by * 64;
    const int r = l & 15;

    const unsigned short* apt[4];
    const unsigned short* bpt[4];
    int wrA[4], wrB[4];
#pragma unroll
    for (int i = 0; i < 4; ++i) {
        int u = tid + 256 * i;
        int row = u >> 4;
        int ku = u & 15;
        int slot = ku ^ (row & 7);
        if (MODE == 1) {
            int g = row_base + m0 + row;
            apt[i] = emb + (size_t)xidx[(g & 63) * SEQ + (g >> 6)] * KTOT + ku * 8;
        } else {
            apt[i] = A + (size_t)(m0 + row) * KTOT + ku * 8;
        }
        bpt[i] = Bw + (size_t)(n0 + row) * KTOT + ku * 8;
        wrA[i] = row * 128 + slot * 8;
        wrB[i] = 8192 + row * 128 + slot * 8;
    }

    f32x4 acc[4] = {};
    bf16x8 va[4], vb[4];

#pragma unroll
    for (int i = 0; i < 4; ++i) va[i] = *(const bf16x8*)(apt[i]);
#pragma unroll
    for (int i = 0; i < 4; ++i) vb[i] = *(const bf16x8*)(bpt[i]);

    constexpr int NKB = KTOT / 128;
#pragma unroll
    for (int kb = 0; kb < NKB; ++kb) {
#pragma unroll
        for (int i = 0; i < 4; ++i) *(bf16x8*)(smem + wrA[i]) = va[i];
#pragma unroll
        for (int i = 0; i < 4; ++i) *(bf16x8*)(smem + wrB[i]) = vb[i];
        __syncthreads();
        if (kb + 1 < NKB) {
            const int ko = (kb + 1) * 128;
#pragma unroll
            for (int i = 0; i < 4; ++i) va[i] = *(const bf16x8*)(apt[i] + ko);
#pragma unroll
            for (int i = 0; i < 4; ++i) vb[i] = *(const bf16x8*)(bpt[i] + ko);
        }
#pragma unroll
        for (int ks = 0; ks < 4; ++ks) {
            const int slot = (ks * 4 + (l >> 4)) ^ (r & 7);
            bf16x8 a = *(const bf16x8*)(smem + (w * 16 + r) * 128 + slot * 8);
#pragma unroll
            for (int nt = 0; nt < 4; ++nt) {
                bf16x8 b = *(const bf16x8*)(smem + 8192 + (nt * 16 + r) * 128 + slot * 8);
                acc[nt] = __builtin_amdgcn_mfma_f32_16x16x32_bf16(a, b, acc[nt], 0, 0, 0);
            }
        }
        __syncthreads();
    }

    const int la = l & 15, rbase = (l >> 4) * 4;
#pragma unroll
    for (int nt = 0; nt < 4; ++nt) {
        int colg = n0 + nt * 16 + la;
        float bsv = bias[colg];
#pragma unroll
        for (int i = 0; i < 4; ++i) {
            int rowg = m0 + w * 16 + rbase + i;
            float v = acc[nt][i] + bsv;
            if (MODE == 2) {
                int g = row_base + rowg;
                int s = g >> 6, b = g & 63;
                Cout[((size_t)(b * SEQ + s)) * NCLS + colg] = v;
            } else {
                Cout[(size_t)rowg * N + colg] = v;
            }
        }
    }
}

// ---------------------------------------------------------------------------
__global__ __launch_bounds__(256)
void gemm_multi(int na, int nb,
                const int* __restrict__ x, const unsigned short* __restrict__ embB,
                const unsigned short* __restrict__ wih0B, const float* __restrict__ bih0,
                float* __restrict__ giA, int rbA,
                const unsigned short* __restrict__ out0b,
                const unsigned short* __restrict__ wih1B, const float* __restrict__ bih1,
                float* __restrict__ giB,
                const unsigned short* __restrict__ out1b,
                const unsigned short* __restrict__ wprojB, const float* __restrict__ bproj,
                float* __restrict__ logits, int rbP) {
    __shared__ unsigned short smem[16384];   // 32 KB
    int bid = blockIdx.x;
    if (bid < na) {
        gemm_dev<1, EMB>(nullptr, wih0B, bih0, giA, GATES, x, embB, rbA,
                         bid % MX, bid / MX, smem);
    } else if (bid < na + nb) {
        int b = bid - na;
        gemm_dev<0, HID>(out0b, wih1B, bih1, giB, GATES, nullptr, nullptr, 0,
                         b % MX, b / MX, smem);
    } else {
        int b = bid - na - nb;
        gemm_dev<2, HID>(out1b, wprojB, bproj, logits, NCLS, nullptr, nullptr, rbP,
                         b % MX, b / MX, smem);
    }
}

// ---------------------------------------------------------------------------
// R11-proven GRU chain body: blob-packed fence-free h exchange,
// drain-before-flag, distributed-flag barrier, w in VGPRs.
// ---------------------------------------------------------------------------
__device__ __forceinline__ void gru_body(int lb,
        const float* __restrict__ gi, const unsigned short* __restrict__ whb,
        const float* __restrict__ b_hh, float* __restrict__ h_f,
        const unsigned short* __restrict__ hb0, const unsigned short* __restrict__ hb1,
        unsigned short* __restrict__ outseq, int* __restrict__ bar, char* smem) {
    float* sg = (float*)(smem + 32768);

    const int bg = lb >> 6;
    const int jt = lb & 63;
    const int b0 = bg * 16, j0 = jt * 16;
    const int tid = threadIdx.x;
    const int w = tid >> 6, l = tid & 63;

    // ---- w slice into VGPRs (gate waves): 16 rows x 1024 K, 32 x bf16x8 ----
    bf16x8 wreg[32];
    if (w < 3) {
        const unsigned short* wrow = whb + (size_t)(w * HID + j0 + (l & 15)) * HID
                                     + ((l >> 4) * 8);
#pragma unroll
        for (int ks = 0; ks < 32; ++ks) wreg[ks] = *(const bf16x8*)(wrow + ks * 32);
    }

    const int prow = tid >> 4, pcol = tid & 15;
    const int pb = b0 + prow, pj = j0 + pcol;
    float hp = h_f[(size_t)pb * HID + pj];
    const float bhr = b_hh[pj], bhz = b_hh[HID + pj], bhn = b_hh[2 * HID + pj];

    const unsigned short* hbuf[2] = {hb0, hb1};

    // consumer h-load geometry: unit u = c*256 + tid  (16B units)
    const int rr = (tid >> 1) & 15;
    const int swr = (rr & 7) << 4;
    char* hdst = smem + rr * 2048 +
                 ((((tid >> 5) << 5) + ((tid & 1) << 4)) ^ swr);

    for (int t = 0; t < TCH; ++t) {
        const unsigned short* hin = hbuf[t & 1];
        unsigned short* hout = (unsigned short*)hbuf[(t + 1) & 1];

        const float* git = gi + ((size_t)(t * BATCH + pb)) * GATES;
        float gir = git[pj];
        float giz = git[HID + pj];
        float gin = git[2 * HID + pj];

        // ---- group h blob: contiguous 32 KB; 8 dense 16B loads/thread ----
        {
            const unsigned short* s0 = hin + ((size_t)bg << 14) + tid * 8;
            bf16x8 h0v, h1v, h2v, h3v, h4v, h5v, h6v, h7v;
            asm volatile(
                "global_load_dwordx4 %0, %8, off sc0 sc1\n\t"
                "global_load_dwordx4 %1, %9, off sc0 sc1\n\t"
                "global_load_dwordx4 %2, %10, off sc0 sc1\n\t"
                "global_load_dwordx4 %3, %11, off sc0 sc1\n\t"
                "global_load_dwordx4 %4, %12, off sc0 sc1\n\t"
                "global_load_dwordx4 %5, %13, off sc0 sc1\n\t"
                "global_load_dwordx4 %6, %14, off sc0 sc1\n\t"
                "global_load_dwordx4 %7, %15, off sc0 sc1"
                : "=&v"(h0v), "=&v"(h1v), "=&v"(h2v), "=&v"(h3v),
                  "=&v"(h4v), "=&v"(h5v), "=&v"(h6v), "=&v"(h7v)
                : "v"(s0), "v"(s0 + 2048), "v"(s0 + 4096), "v"(s0 + 6144),
                  "v"(s0 + 8192), "v"(s0 + 10240), "v"(s0 + 12288), "v"(s0 + 14336));
            asm volatile("s_waitcnt vmcnt(0)" ::: "memory");
            __builtin_amdgcn_sched_barrier(0);
            *(bf16x8*)(hdst + 0 * 256) = h0v; *(bf16x8*)(hdst + 1 * 256) = h1v;
            *(bf16x8*)(hdst + 2 * 256) = h2v; *(bf16x8*)(hdst + 3 * 256) = h3v;
            *(bf16x8*)(hdst + 4 * 256) = h4v; *(bf16x8*)(hdst + 5 * 256) = h5v;
            *(bf16x8*)(hdst + 6 * 256) = h6v; *(bf16x8*)(hdst + 7 * 256) = h7v;
        }
        __syncthreads();

        if (w < 3) {
            const int r = l & 15;
            const int sw = (r & 7) << 4;
            const int kq = (l >> 4) * 16;
            const int hbyte = r * 2048;
            f32x4 acc = {};
#pragma unroll
            for (int ks = 0; ks < 32; ++ks) {
                bf16x8 a = *(const bf16x8*)(smem + hbyte + ((ks * 64 + kq) ^ sw));
                acc = __builtin_amdgcn_mfma_f32_16x16x32_bf16(a, wreg[ks], acc, 0, 0, 0);
            }
            const int col = l & 15, rbase = (l >> 4) * 4;
#pragma unroll
            for (int i = 0; i < 4; ++i) sg[w * 256 + (rbase + i) * 16 + col] = acc[i];
        }
        __syncthreads();

        // ---- pointwise ----
        float ghr = sg[0 * 256 + tid] + bhr;
        float ghz = sg[1 * 256 + tid] + bhz;
        float ghn = sg[2 * 256 + tid] + bhn;
        float rr2 = 1.f / (1.f + __expf(-(gir + ghr)));
        float zz = 1.f / (1.f + __expf(-(giz + ghz)));
        float nn = tanhf(gin + rr2 * ghn);
        hp = (1.f - zz) * nn + zz * hp;
        unsigned short hb = f2bf(hp);
        outseq[((size_t)(t * BATCH + pb)) * HID + pj] = hb;

        // ---- pack own bf16 into LDS (h region dead until next load) ----
        *(unsigned short*)(smem + tid * 2) = hb;
        __syncthreads();

        // ---- wave-0: 32 x dwordx4 full-line blob store + drain ----
        if (tid < 32) {
            bf16x8 pk = *(const bf16x8*)(smem + tid * 16);
            unsigned short* dstp = hout + ((size_t)(bg * 64 + jt) << 8) + tid * 8;
            asm volatile(
                "global_store_dwordx4 %0, %1, off sc0 sc1\n\t"
                "s_waitcnt vmcnt(0)"
                :: "v"(dstp), "v"(pk) : "memory");
        }

        if (t < TCH - 1) {
            if (tid == 0) {
                __hip_atomic_store(bar + (((bg << 6) | jt) << 4), t + 1,
                                   __ATOMIC_RELAXED, __HIP_MEMORY_SCOPE_AGENT);
            }
            if (tid < 64) {
                const int* f = bar + (((bg << 6) | tid) << 4);
                while (!__all(__hip_atomic_load(f, __ATOMIC_RELAXED,
                                                __HIP_MEMORY_SCOPE_AGENT) > t)) {
                    __builtin_amdgcn_s_sleep(1);
                }
            }
            __syncthreads();
        }
    }

    h_f[(size_t)pb * HID + pj] = hp;
}

// ---------------------------------------------------------------------------
// MEGA launch: [0,g0) gru layer0 | [g0,g0+g1) gru layer1 | then riders:
// na gi0-gather blocks, nb gi1 blocks, np proj blocks. Riders are fully
// independent (all inputs finalized in previous launches) — no polling.
// ---------------------------------------------------------------------------
__global__ __launch_bounds__(256, 2)
void mega(int g0, int g1, int na, int nb, int np,
          const float* __restrict__ gi0, const unsigned short* __restrict__ wh0,
          const float* __restrict__ bh0, float* __restrict__ h0f,
          unsigned short* __restrict__ h0p, unsigned short* __restrict__ h0q,
          unsigned short* __restrict__ out0, int* __restrict__ bar0,
          const float* __restrict__ gi1, const unsigned short* __restrict__ wh1,
          const float* __restrict__ bh1, float* __restrict__ h1f,
          unsigned short* __restrict__ h1p, unsigned short* __restrict__ h1q,
          unsigned short* __restrict__ out1, int* __restrict__ bar1,
          const int* __restrict__ x, const unsigned short* __restrict__ embB,
          const unsigned short* __restrict__ wih0B, const float* __restrict__ bih0,
          float* __restrict__ giA_nxt, int rbA,
          const unsigned short* __restrict__ out0_prev,
          const unsigned short* __restrict__ wih1B, const float* __restrict__ bih1,
          float* __restrict__ giB_nxt,
          const unsigned short* __restrict__ out1_old,
          const unsigned short* __restrict__ wprojB, const float* __restrict__ bproj,
          float* __restrict__ logits, int rbP) {
    __shared__ char smem[35840];          // gru: h 32K + sg 3K; gemm uses 32K
    const int bid = blockIdx.x;
    const int ng = g0 + g1;
    if (bid < ng) {
        if (bid < g0)
            gru_body(bid, gi0, wh0, bh0, h0f, h0p, h0q, out0, bar0, smem);
        else
            gru_body(bid - g0, gi1, wh1, bh1, h1f, h1p, h1q, out1, bar1, smem);
    } else {
        int b2 = bid - ng;
        if (b2 < na) {
            gemm_dev<1, EMB>(nullptr, wih0B, bih0, giA_nxt, GATES, x, embB, rbA,
                             b2 % MX, b2 / MX, (unsigned short*)smem);
        } else if (b2 < na + nb) {
            int b = b2 - na;
            gemm_dev<0, HID>(out0_prev, wih1B, bih1, giB_nxt, GATES, nullptr, nullptr, 0,
                             b % MX, b / MX, (unsigned short*)smem);
        } else {
            int b = b2 - na - nb;
            gemm_dev<2, HID>(out1_old, wprojB, bproj, logits, NCLS, nullptr, nullptr, rbP,
                             b % MX, b / MX, (unsigned short*)smem);
        }
    }
}

// ---------------------------------------------------------------------------
extern "C" void kernel_launch(void* const* d_in, const int* in_sizes, int n_in,
                              void* d_out, int out_size, void* d_ws, size_t ws_size,
                              hipStream_t stream) {
    const int*   x      = (const int*)d_in[0];
    const float* hs     = (const float*)d_in[1];
    const float* emb    = (const float*)d_in[2];
    const float* w_ih0  = (const float*)d_in[3];
    const float* w_hh0  = (const float*)d_in[4];
    const float* b_ih0  = (const float*)d_in[5];
    const float* b_hh0  = (const float*)d_in[6];
    const float* w_ih1  = (const float*)d_in[7];
    const float* w_hh1  = (const float*)d_in[8];
    const float* b_ih1  = (const float*)d_in[9];
    const float* b_hh1  = (const float*)d_in[10];
    const float* w_proj = (const float*)d_in[11];
    const float* b_proj = (const float*)d_in[12];

    float* logits = (float*)d_out;                       // [B*S, 128] f32
    float* hT     = logits + (size_t)SEQ * BATCH * NCLS; // [2, 64, 1024] f32

    const size_t GI_BYTES = (size_t)ROWS * GATES * 4;    // 12.58 MB
    const bool big = ws_size >= ((size_t)82 << 20);      // mega path needs ~81 MB

    char* p = (char*)d_ws;
    float* giA[2]; float* giB[2];
    giA[0] = (float*)p; p += GI_BYTES;
    giA[1] = big ? (float*)p : giA[0]; if (big) p += GI_BYTES;
    giB[0] = (float*)p; p += GI_BYTES;
    giB[1] = big ? (float*)p : giB[0]; if (big) p += GI_BYTES;
    float* h0f = (float*)p;                     p += 65536 * 4;
    float* h1f = (float*)p;                     p += 65536 * 4;
    unsigned short* h0b0 = (unsigned short*)p;  p += 65536 * 2;
    unsigned short* h0b1 = (unsigned short*)p;  p += 65536 * 2;
    unsigned short* h1b0 = (unsigned short*)p;  p += 65536 * 2;
    unsigned short* h1b1 = (unsigned short*)p;  p += 65536 * 2;
    unsigned short* out0b[2];
    out0b[0] = (unsigned short*)p;              p += (size_t)ROWS * HID * 2;
    out0b[1] = big ? (unsigned short*)p : out0b[0]; if (big) p += (size_t)ROWS * HID * 2;
    unsigned short* out1b[2];
    out1b[0] = (unsigned short*)p;              p += (size_t)ROWS * HID * 2;
    out1b[1] = (unsigned short*)p;              p += (size_t)ROWS * HID * 2;
    unsigned short* embB  = (unsigned short*)p; p += (size_t)NCLS * EMB * 2;
    unsigned short* wih0B = (unsigned short*)p; p += (size_t)GATES * EMB * 2;
    unsigned short* whh0B = (unsigned short*)p; p += (size_t)GATES * HID * 2;
    unsigned short* wih1B = (unsigned short*)p; p += (size_t)GATES * HID * 2;
    unsigned short* whh1B = (unsigned short*)p; p += (size_t)GATES * HID * 2;
    unsigned short* wprojB = (unsigned short*)p; p += (size_t)NCLS * HID * 2;
    int* bar = (int*)p;                         p += (size_t)32 * 4096 * 4;

    hipMemsetAsync(bar, 0, (size_t)32 * 4096 * 4, stream);

    conv_all<<<10272, 256, 0, stream>>>(emb, w_ih0, w_hh0, w_ih1, w_hh1, w_proj, hs,
                                        embB, wih0B, whh0B, wih1B, whh1B, wprojB,
                                        h0b0, h1b0, h0f, h1f);

    if (big) {
        // prologue: gi0(0) into giA[0]
        gemm_multi<<<768, 256, 0, stream>>>(768, 0,
            x, embB, wih0B, b_ih0, giA[0], 0,
            out0b[0], wih1B, b_ih1, giB[0],
            out1b[0], wprojB, b_proj, logits, 0);

        // deep pipeline: mega(k) = gru0(k) | gru1(k-2) | gi0(k+1) | gi1(k-1) | proj(k-3)
        for (int k = 0; k < 18; ++k) {
            int g0 = (k <= 15) ? 256 : 0;
            int g1 = (k >= 2) ? 256 : 0;
            int na = (k <= 14) ? 768 : 0;
            int nb = (k >= 1 && k <= 16) ? 768 : 0;
            int np = (k >= 3) ? 32 : 0;
            int m = k - 2, n = k - 1, q = k - 3;
            mega<<<g0 + g1 + na + nb + np, 256, 0, stream>>>(
                g0, g1, na, nb, np,
                giA[k & 1], whh0B, b_hh0, h0f, h0b0, h0b1, out0b[k & 1],
                bar + (size_t)(k & 15) * 4096,
                giB[m & 1], whh1B, b_hh1, h1f, h1b0, h1b1, out1b[m & 1],
                bar + (size_t)(16 + (m & 15)) * 4096,
                x, embB, wih0B, b_ih0, giA[(k + 1) & 1], (k + 1) * ROWS,
                out0b[n & 1], wih1B, b_ih1, giB[n & 1],
                out1b[q & 1], wprojB, b_proj, logits, q * ROWS);
        }

        // epilogue: proj(15)
        gemm_multi<<<32, 256, 0, stream>>>(0, 0,
            x, embB, wih0B, b_ih0, giA[0], 0,
            out0b[0], wih1B, b_ih1, giB[0],
            out1b[1], wprojB, b_proj, logits, 15 * ROWS);
    } else {
        // R11 fallback schedule (single-buffered giA/giB/out0b)
        for (int c = 0; c < NCH; ++c) {
            int na = 768;
            int nb = (c >= 1) ? 768 : 0;
            int np = (c >= 2) ? 32 : 0;
            gemm_multi<<<na + nb + np, 256, 0, stream>>>(na, nb,
                x, embB, wih0B, b_ih0, giA[0], c * ROWS,
                out0b[0], wih1B, b_ih1, giB[0],
                out1b[(c - 2) & 1], wprojB, b_proj, logits,
                (c >= 2) ? (c - 2) * ROWS : 0);

            int g1 = (c >= 1) ? 256 : 0;
            int c1 = (c >= 1) ? c - 1 : 0;
            mega<<<256 + g1, 256, 0, stream>>>(256, g1, 0, 0, 0,
                giA[0], whh0B, b_hh0, h0f, h0b0, h0b1, out0b[0],
                bar + (size_t)c * 4096,
                giB[0], whh1B, b_hh1, h1f, h1b0, h1b1, out1b[c1 & 1],
                bar + (size_t)(16 + c1) * 4096,
                x, embB, wih0B, b_ih0, giA[0], 0,
                out0b[0], wih1B, b_ih1, giB[0],
                out1b[0], wprojB, b_proj, logits, 0);
        }
        gemm_multi<<<768 + 32, 256, 0, stream>>>(0, 768,
            x, embB, wih0B, b_ih0, giA[0], 0,
            out0b[0], wih1B, b_ih1, giB[0],
            out1b[0], wprojB, b_proj, logits, 14 * ROWS);
        mega<<<256, 256, 0, stream>>>(0, 256, 0, 0, 0,
            giA[0], whh0B, b_hh0, h0f, h0b0, h0b1, out0b[0], bar,
            giB[0], whh1B, b_hh1, h1f, h1b0, h1b1, out1b[1],
            bar + (size_t)31 * 4096,
            x, embB, wih0B, b_ih0, giA[0], 0,
            out0b[0], wih1B, b_ih1, giB[0],
            out1b[0], wprojB, b_proj, logits, 0);
        gemm_multi<<<32, 256, 0, stream>>>(0, 0,
            x, embB, wih0B, b_ih0, giA[0], 0,
            out0b[0], wih1B, b_ih1, giB[0],
            out1b[1], wprojB, b_proj, logits, 15 * ROWS);
    }

    hipMemcpyAsync(hT, h0f, 65536 * 4, hipMemcpyDeviceToDevice, stream);
    hipMemcpyAsync(hT + 65536, h1f, 65536 * 4, hipMemcpyDeviceToDevice, stream);
}